// Round 12
// baseline (71.566 us; speedup 1.0000x reference)
//
#include <hip/hip_runtime.h>
#include <hip/hip_bf16.h>
#include <stdint.h>

typedef __bf16 bf16x8 __attribute__((ext_vector_type(8)));
typedef float  f32x4  __attribute__((ext_vector_type(4)));
typedef unsigned short u16x8 __attribute__((ext_vector_type(8)));

#define NB 32
#define NC 128
#define NH 56
#define NW 56
#define NK 4
#define NCO 128
#define NCR 32
#define NHW 3136
#define TEMPER 30.0f

// ws byte offsets
#define WS_ATTN   0u         // 512 B
#define WS_BC     4096u      // 16 KB
#define WS_ROWSUM 65536u     // f32 [32][58][128] = 950,272 B
#define WS_WC     1048576u   // bf16 [32][9][128][128] = 9,437,184 B
#define WS_XT     10485760u  // bf16 [32][58][58][128] = 27,557,888 B

// fp32 NCHW -> bf16 [b][hp=58][wp=58][c=128] with zero halo, via LDS transpose.
// XCD-aligned to conv's b-map. Emits rowsum (pool fused).
__global__ void xt_kernel(const float* __restrict__ x, __hip_bfloat16* __restrict__ xt,
                          float* __restrict__ rowsum) {
  __shared__ float lds[58 * 133];
  int xcd = blockIdx.x & 7;
  int j   = blockIdx.x >> 3;               // 0..231
  int b   = xcd * 4 + j / 58;
  int hp  = j % 58;
  int blk = b * 58 + hp;
  int h = hp - 1;
  bool hin = (h >= 0) && (h < NH);
  int tid = threadIdx.x;
  if (hin) {
    const float* xrow = x + ((size_t)b * NC) * NHW + (size_t)h * NW;
    for (int i = tid; i < 128 * 14; i += 256) {
      int c = i / 14;
      int w4 = (i - c * 14) * 4;
      float4 v = *(const float4*)(xrow + (size_t)c * NHW + w4);
      int base = (w4 + 1) * 133 + c;
      lds[base]         = v.x;
      lds[base + 133]   = v.y;
      lds[base + 2*133] = v.z;
      lds[base + 3*133] = v.w;
    }
  }
  __syncthreads();
  __hip_bfloat16* orow = xt + (size_t)blk * (58 * 128);
  for (int i = tid; i < 58 * 16; i += 256) {
    int wp = i >> 4;
    int cg = (i & 15) << 3;
    u16x8 o;
    if (!hin || wp == 0 || wp == 57) {
      o = (u16x8)0;
    } else {
      const float* src = lds + wp * 133 + cg;
      #pragma unroll
      for (int jx = 0; jx < 8; ++jx) {
        union { __hip_bfloat16 b; unsigned short u; } cv;
        cv.b = __float2bfloat16(src[jx]);
        o[jx] = cv.u;
      }
    }
    *(u16x8*)(orow + wp * 128 + cg) = o;
  }
  if (hin && tid < 128) {
    float s = 0.f;
    #pragma unroll 8
    for (int wp = 1; wp <= 56; ++wp) s += lds[wp * 133 + tid];
    rowsum[(size_t)blk * 128 + tid] = s;
  }
}

__global__ void attn_kernel(const float* __restrict__ rowsum, const float* __restrict__ aw1,
                            const float* __restrict__ aw2, const float* __restrict__ bias,
                            float* __restrict__ attn, float* __restrict__ bc_out) {
  int b = blockIdx.x;
  __shared__ float sp[NC], h1[NCR], at[NK];
  int t = threadIdx.x;
  if (t < NC) {
    float s = 0.f;
    for (int hp = 1; hp <= 56; ++hp) s += rowsum[((size_t)b * 58 + hp) * 128 + t];
    sp[t] = s * (1.0f / (float)NHW);
  }
  __syncthreads();
  if (t < NCR) {
    float s = 0.f;
    for (int c = 0; c < NC; ++c) s += aw1[t*NC + c] * sp[c];
    h1[t] = s > 0.f ? s : 0.f;
  }
  __syncthreads();
  if (t == 0) {
    float lg[NK], mx = -1e30f;
    for (int k = 0; k < NK; ++k) {
      float s = 0.f;
      for (int r = 0; r < NCR; ++r) s += aw2[k*NCR + r] * h1[r];
      lg[k] = s * (1.0f/TEMPER);
      mx = fmaxf(mx, lg[k]);
    }
    float den = 0.f, e[NK];
    for (int k = 0; k < NK; ++k) { e[k] = expf(lg[k]-mx); den += e[k]; }
    float inv = 1.0f/den;
    for (int k = 0; k < NK; ++k) { at[k] = e[k]*inv; attn[b*NK+k] = at[k]; }
  }
  __syncthreads();
  if (t < NCO) {
    float s = 0.f;
    for (int k = 0; k < NK; ++k) s += at[k] * bias[k*NCO + t];
    bc_out[b*NCO + t] = s;
  }
}

__global__ void combine_kernel(const float* __restrict__ W, const float* __restrict__ attn,
                               __hip_bfloat16* __restrict__ wc) {
  int gid = blockIdx.x;                     // 256 blocks
  int bg  = gid >> 6;
  int tcell = (gid & 63) * 256 + threadIdx.x;
  int co = tcell >> 7, ci = tcell & 127;
  float w[4][9];
  const float* wp = W + ((size_t)co * 128 + ci) * 9;
  #pragma unroll
  for (int k = 0; k < 4; ++k)
    #pragma unroll
    for (int j = 0; j < 9; ++j)
      w[k][j] = wp[(size_t)k * 147456 + j];
  for (int b = bg * 8; b < bg * 8 + 8; ++b) {
    float a0 = attn[b*4+0], a1 = attn[b*4+1], a2 = attn[b*4+2], a3 = attn[b*4+3];
    #pragma unroll
    for (int j = 0; j < 9; ++j) {
      float v = a0*w[0][j] + a1*w[1][j] + a2*w[2][j] + a3*w[3][j];
      wc[(((size_t)b*9 + j) * 128 + co) * 128 + ci] = __float2bfloat16(v);
    }
  }
}

// ------------------------------ conv ------------------------------
// R7's proven serial-stage structure at m97's OCCUPANCY OPERATING POINT:
// 256-thread blocks, wave = 32co x 112pos (acc 56 regs -> ~130 total regs),
// __launch_bounds__(256,3) -> 3 waves/SIMD, 3 blocks/CU, 12 waves/CU.
// Cross-block TLP hides the stage drains / barriers / epilogue that were
// fully serialized at 1 block/CU (the 40us invariant of R7-R10).
// Block = 128co x 112pos (2 out rows), grid 896 (8 XCD x 112, XCD-aligned).
// LDS: B 4 padded rows (20.5KB incl clamp-pad) + A 3-khw slab (24.6KB) = 44KB.
// Inner loop: pure ds_read + MFMA (both operands from LDS; uniform bank spread).
#define RS 2368            // B row stride in shorts (296 16B-slots, %8==0)
#define CS 40              // B col cell stride in shorts
#define BCHP 1280          // B chunk slots incl pad (1184 data + clamp spill)
#define ACH 1536           // A chunks per 3-khw slab

#define GLOAD16(src, dst) \
  __builtin_amdgcn_global_load_lds( \
    (const __attribute__((address_space(1))) unsigned int*)(src), \
    (__attribute__((address_space(3))) unsigned int*)(dst), 16, 0, 0)

__global__ __launch_bounds__(256, 3) void conv_kernel(
    const unsigned short* __restrict__ xt,
    const unsigned short* __restrict__ wc,
    const float* __restrict__ bc,
    float* __restrict__ out) {
  __shared__ __align__(16) unsigned short lds_b[BCHP*8];   // 20,480 B
  __shared__ __align__(16) unsigned short lds_a[ACH*8];    // 24,576 B
  const int tid  = threadIdx.x;        // 0..255
  const int lane = tid & 63;
  const int wm   = tid >> 6;           // 0..3: co strip *32
  const int bid  = blockIdx.x;         // 896 = 8*112
  const int xcd  = bid & 7;
  const int jj   = bid >> 3;           // 0..111
  const int b    = xcd*4 + jj/28;
  const int r0   = (jj % 28) * 2;      // 2 out rows per block
  const int li   = lane & 15;
  const int kg   = lane >> 4;

  // B staging map: 4 rows x 296 slots = 1184 chunks; 5 iters (clamped to pad)
  int srcB[5];
  #pragma unroll
  for (int i = 0; i < 5; ++i) {
    int q = i*256 + tid;               // 0..1279
    int r = q / 296;
    int sl = q - r*296;
    int col = sl / 5;
    int part = sl - col*5;
    int rc = r > 3 ? 3 : r;
    int cl = col > 57 ? 57 : col;
    int pc = part > 3 ? 3 : part;
    srcB[i] = ((r0 + rc)*58 + cl)*128 + pc*8;
  }
  // A staging map: 3 khwL x 128 co x 4 parts = 1536 chunks; 6 iters exact.
  // LDS layout linear: chunk c -> [khwL][co][32ci], conflict-free reads.
  int srcA[6];
  #pragma unroll
  for (int i = 0; i < 6; ++i) {
    int c = i*256 + tid;
    int khwL = c >> 9;
    int co   = (c & 511) >> 2;
    int part = c & 3;
    srcA[i] = (khwL*128 + co)*128 + part*8;   // + kh*49152 + cc*32 at stage
  }

  int xoff[7];
  #pragma unroll
  for (int f = 0; f < 7; ++f) {
    int pos = f*16 + li;               // 0..111
    int rB = pos / 56;
    int cB = pos - rB*56;
    xoff[f] = rB*RS + cB*CS + kg*8;
  }
  const int aRead = (wm*32 + li)*32 + kg*8;  // + mo*512 + kwl*4096

  const f32x4 vzero = {0.f, 0.f, 0.f, 0.f};
  f32x4 acc[2][7];
  #pragma unroll
  for (int mo = 0; mo < 2; ++mo)
    #pragma unroll
    for (int f = 0; f < 7; ++f) acc[mo][f] = vzero;

  const unsigned short* xtg = xt + (size_t)b*(58*58*128);
  const unsigned short* wcg = wc + (size_t)b*(9*128*128);

  for (int cc = 0; cc < 4; ++cc) {
    #pragma unroll
    for (int kh = 0; kh < 3; ++kh) {
      __syncthreads();                 // readers of lds_a (and lds_b at cc turn) done
      #pragma unroll
      for (int i = 0; i < 6; ++i)
        GLOAD16(wcg + kh*49152 + srcA[i] + cc*32, lds_a + (i*256 + wm*64)*8);
      if (kh == 0) {
        #pragma unroll
        for (int i = 0; i < 5; ++i)
          GLOAD16(xtg + srcB[i] + cc*32, lds_b + (i*256 + wm*64)*8);
      }
      __syncthreads();                 // staged data ready
      #pragma unroll
      for (int kwl = 0; kwl < 3; ++kwl) {
        bf16x8 af[2];
        #pragma unroll
        for (int mo = 0; mo < 2; ++mo)
          af[mo] = *(const bf16x8*)(lds_a + kwl*4096 + aRead + mo*512);
        bf16x8 bfr[7];
        #pragma unroll
        for (int f = 0; f < 7; ++f)
          bfr[f] = *(const bf16x8*)(lds_b + xoff[f] + kh*RS + kwl*CS);
        #pragma unroll
        for (int mo = 0; mo < 2; ++mo)
          #pragma unroll
          for (int f = 0; f < 7; ++f)
            acc[mo][f] = __builtin_amdgcn_mfma_f32_16x16x32_bf16(af[mo], bfr[f], acc[mo][f], 0, 0, 0);
      }
    }
  }

  float* ob = out + (size_t)b*NCO*NHW;
  #pragma unroll
  for (int mo = 0; mo < 2; ++mo) {
    #pragma unroll
    for (int rg = 0; rg < 4; ++rg) {
      const int co = wm*32 + mo*16 + kg*4 + rg;
      const float bv = bc[b*NCO + co];
      float* orow = ob + (size_t)co*NHW;
      #pragma unroll
      for (int f = 0; f < 7; ++f) {
        int pos = f*16 + li;
        int rB = pos / 56;
        int cB = pos - rB*56;
        orow[(r0 + rB)*56 + cB] = acc[mo][f][rg] + bv;
      }
    }
  }
}

extern "C" void kernel_launch(void* const* d_in, const int* in_sizes, int n_in,
                              void* d_out, int out_size, void* d_ws, size_t ws_size,
                              hipStream_t stream) {
  const float* x   = (const float*)d_in[0];
  const float* W   = (const float*)d_in[1];
  const float* bia = (const float*)d_in[2];
  const float* aw1 = (const float*)d_in[3];
  const float* aw2 = (const float*)d_in[4];
  float* out = (float*)d_out;
  char* ws = (char*)d_ws;
  float* attn   = (float*)(ws + WS_ATTN);
  float* bcm    = (float*)(ws + WS_BC);
  float* rowsum = (float*)(ws + WS_ROWSUM);
  __hip_bfloat16* wc = (__hip_bfloat16*)(ws + WS_WC);
  __hip_bfloat16* xt = (__hip_bfloat16*)(ws + WS_XT);

  xt_kernel<<<NB*58, 256, 0, stream>>>(x, xt, rowsum);
  attn_kernel<<<NB, 128, 0, stream>>>(rowsum, aw1, aw2, bia, attn, bcm);
  combine_kernel<<<256, 256, 0, stream>>>(W, attn, wc);
  conv_kernel<<<896, 256, 0, stream>>>((const unsigned short*)xt,
                                       (const unsigned short*)wc, bcm, out);
}

// Round 13
// 66.263 us; speedup vs baseline: 1.0800x; 1.0800x over previous
//
#include <hip/hip_runtime.h>
#include <hip/hip_bf16.h>
#include <stdint.h>

typedef __bf16 bf16x8 __attribute__((ext_vector_type(8)));
typedef float  f32x4  __attribute__((ext_vector_type(4)));
typedef unsigned short u16x8 __attribute__((ext_vector_type(8)));
typedef unsigned int   u32x4 __attribute__((ext_vector_type(4)));

#define NB 32
#define NC 128
#define NH 56
#define NW 56
#define NK 4
#define NCO 128
#define NCR 32
#define NHW 3136
#define TEMPER 30.0f

// ws byte offsets
#define WS_ATTN   0u         // 512 B
#define WS_BC     4096u      // 16 KB
#define WS_ROWSUM 65536u     // f32 [32][58][128] = 950,272 B
#define WS_WC     1048576u   // bf16 [32][9][128][128] = 9,437,184 B
#define WS_XT     10485760u  // bf16 [32][58][58][128] = 27,557,888 B

// fp32 NCHW -> bf16 [b][hp=58][wp=58][c=128] with zero halo, via LDS transpose.
// XCD-aligned to conv's b-map. Emits rowsum (pool fused).
__global__ void xt_kernel(const float* __restrict__ x, __hip_bfloat16* __restrict__ xt,
                          float* __restrict__ rowsum) {
  __shared__ float lds[58 * 133];
  int xcd = blockIdx.x & 7;
  int j   = blockIdx.x >> 3;               // 0..231
  int b   = xcd * 4 + j / 58;
  int hp  = j % 58;
  int blk = b * 58 + hp;
  int h = hp - 1;
  bool hin = (h >= 0) && (h < NH);
  int tid = threadIdx.x;
  if (hin) {
    const float* xrow = x + ((size_t)b * NC) * NHW + (size_t)h * NW;
    for (int i = tid; i < 128 * 14; i += 256) {
      int c = i / 14;
      int w4 = (i - c * 14) * 4;
      float4 v = *(const float4*)(xrow + (size_t)c * NHW + w4);
      int base = (w4 + 1) * 133 + c;
      lds[base]         = v.x;
      lds[base + 133]   = v.y;
      lds[base + 2*133] = v.z;
      lds[base + 3*133] = v.w;
    }
  }
  __syncthreads();
  __hip_bfloat16* orow = xt + (size_t)blk * (58 * 128);
  for (int i = tid; i < 58 * 16; i += 256) {
    int wp = i >> 4;
    int cg = (i & 15) << 3;
    u16x8 o;
    if (!hin || wp == 0 || wp == 57) {
      o = (u16x8)0;
    } else {
      const float* src = lds + wp * 133 + cg;
      #pragma unroll
      for (int jx = 0; jx < 8; ++jx) {
        union { __hip_bfloat16 b; unsigned short u; } cv;
        cv.b = __float2bfloat16(src[jx]);
        o[jx] = cv.u;
      }
    }
    *(u16x8*)(orow + wp * 128 + cg) = o;
  }
  if (hin && tid < 128) {
    float s = 0.f;
    #pragma unroll 8
    for (int wp = 1; wp <= 56; ++wp) s += lds[wp * 133 + tid];
    rowsum[(size_t)blk * 128 + tid] = s;
  }
}

__global__ void attn_kernel(const float* __restrict__ rowsum, const float* __restrict__ aw1,
                            const float* __restrict__ aw2, const float* __restrict__ bias,
                            float* __restrict__ attn, float* __restrict__ bc_out) {
  int b = blockIdx.x;
  __shared__ float sp[NC], h1[NCR], at[NK];
  int t = threadIdx.x;
  if (t < NC) {
    float s = 0.f;
    for (int hp = 1; hp <= 56; ++hp) s += rowsum[((size_t)b * 58 + hp) * 128 + t];
    sp[t] = s * (1.0f / (float)NHW);
  }
  __syncthreads();
  if (t < NCR) {
    float s = 0.f;
    for (int c = 0; c < NC; ++c) s += aw1[t*NC + c] * sp[c];
    h1[t] = s > 0.f ? s : 0.f;
  }
  __syncthreads();
  if (t == 0) {
    float lg[NK], mx = -1e30f;
    for (int k = 0; k < NK; ++k) {
      float s = 0.f;
      for (int r = 0; r < NCR; ++r) s += aw2[k*NCR + r] * h1[r];
      lg[k] = s * (1.0f/TEMPER);
      mx = fmaxf(mx, lg[k]);
    }
    float den = 0.f, e[NK];
    for (int k = 0; k < NK; ++k) { e[k] = expf(lg[k]-mx); den += e[k]; }
    float inv = 1.0f/den;
    for (int k = 0; k < NK; ++k) { at[k] = e[k]*inv; attn[b*NK+k] = at[k]; }
  }
  __syncthreads();
  if (t < NCO) {
    float s = 0.f;
    for (int k = 0; k < NK; ++k) s += at[k] * bias[k*NCO + t];
    bc_out[b*NCO + t] = s;
  }
}

__global__ void combine_kernel(const float* __restrict__ W, const float* __restrict__ attn,
                               __hip_bfloat16* __restrict__ wc) {
  int gid = blockIdx.x;                     // 256 blocks
  int bg  = gid >> 6;
  int tcell = (gid & 63) * 256 + threadIdx.x;
  int co = tcell >> 7, ci = tcell & 127;
  float w[4][9];
  const float* wp = W + ((size_t)co * 128 + ci) * 9;
  #pragma unroll
  for (int k = 0; k < 4; ++k)
    #pragma unroll
    for (int j = 0; j < 9; ++j)
      w[k][j] = wp[(size_t)k * 147456 + j];
  for (int b = bg * 8; b < bg * 8 + 8; ++b) {
    float a0 = attn[b*4+0], a1 = attn[b*4+1], a2 = attn[b*4+2], a3 = attn[b*4+3];
    #pragma unroll
    for (int j = 0; j < 9; ++j) {
      float v = a0*w[0][j] + a1*w[1][j] + a2*w[2][j] + a3*w[3][j];
      wc[(((size_t)b*9 + j) * 128 + co) * 128 + ci] = __float2bfloat16(v);
    }
  }
}

// ------------------------------ conv ------------------------------
// All three verified levers in one kernel:
//  (a) R7 compute geometry: wave = 64co x 112pos -> 11 ds_read_b128 per
//      28 MFMA (best LDS:MFMA ratio tried).
//  (b) A-frag bank fix: A reg-staged (issue-early/write-late, T14) into
//      PADDED 80B co-stride layout -> start-bank 20*li mod 32 (period 8),
//      conflict-free. (R8-R11 used linear 64B stride = 8-way conflict.)
//  (c) True 2 blocks/CU: 256-thread blocks, LDS 59KB, grid 448 -> neighbor
//      blocks run phase-offset and fill each other's stage/drain gaps (m114).
// Block = 128co x 224pos (4 out rows), 4 waves (2m x 2n), grid 448.
#define RS 2368            // B row stride in shorts (296 16B-slots, %8==0)
#define CS 40              // B col cell stride in shorts
#define ACS 40             // A co stride in shorts (80B, conflict-free)
#define AKWS (128*ACS)     // A kwl slab stride in shorts (5120)

#define GLOAD16(src, dst) \
  __builtin_amdgcn_global_load_lds( \
    (const __attribute__((address_space(1))) unsigned int*)(src), \
    (__attribute__((address_space(3))) unsigned int*)(dst), 16, 0, 0)

__global__ __launch_bounds__(256, 2) void conv_kernel(
    const unsigned short* __restrict__ xt,
    const unsigned short* __restrict__ wc,
    const float* __restrict__ bc,
    float* __restrict__ out) {
  __shared__ __align__(16) unsigned short lds_b[1792*8];   // 28,672 B (6 rows + pad)
  __shared__ __align__(16) unsigned short lds_a[3*AKWS];   // 30,720 B (3 kwl x 128co x pad40)
  const int tid  = threadIdx.x;        // 0..255
  const int lane = tid & 63;
  const int wv   = tid >> 6;           // 0..3
  const int wm   = wv & 1;             // co strip *64
  const int wn   = wv >> 1;            // pos strip *112
  const int bid  = blockIdx.x;         // 448 = 8 xcd * 56
  const int xcd  = bid & 7;
  const int jj   = bid >> 3;           // 0..55
  const int b    = xcd*4 + jj/14;
  const int r0   = (jj % 14) * 4;      // 4 out rows per block
  const int li   = lane & 15;
  const int kg   = lane >> 4;

  // B staging map: 6 rows x 296 slots = 1776 chunks; 7 iters x 256 (clamped)
  int srcB[7];
  #pragma unroll
  for (int i = 0; i < 7; ++i) {
    int q = i*256 + tid;               // 0..1791
    int r = q / 296;
    int sl = q - r*296;
    int col = sl / 5;
    int part = sl - col*5;
    int rc = r > 5 ? 5 : r;
    int cl = col > 57 ? 57 : col;
    int pc = part > 3 ? 3 : part;
    srcB[i] = ((r0 + rc)*58 + cl)*128 + pc*8;
  }
  // A staging map: per kh: 3 kwl x 128 co x 4 parts = 1536 chunks; 6 x 256 exact.
  // Source offset (global, +kh/cc at use); dest PADDED (kwl*AKWS + co*40 + part*8).
  int srcA[6], dstA[6];
  #pragma unroll
  for (int i = 0; i < 6; ++i) {
    int c = i*256 + tid;
    int kwl  = c >> 9;
    int co   = (c & 511) >> 2;
    int part = c & 3;
    srcA[i] = (kwl*128 + co)*128 + part*8;     // + kh*49152 + cc*32
    dstA[i] = kwl*AKWS + co*ACS + part*8;
  }

  int xoff[7];
  #pragma unroll
  for (int f = 0; f < 7; ++f) {
    int pos = wn*112 + f*16 + li;      // 0..223
    int rB = pos / 56;
    int cB = pos - rB*56;
    xoff[f] = rB*RS + cB*CS + kg*8;
  }
  const int aRead = (wm*64 + li)*ACS + kg*8;   // + mo*16*ACS + kwl*AKWS

  const f32x4 vzero = {0.f, 0.f, 0.f, 0.f};
  f32x4 acc[4][7];
  #pragma unroll
  for (int mo = 0; mo < 4; ++mo)
    #pragma unroll
    for (int f = 0; f < 7; ++f) acc[mo][f] = vzero;

  const unsigned short* xtg = xt + (size_t)b*(58*58*128);
  const unsigned short* wcg = wc + (size_t)b*(9*128*128);

  for (int cc = 0; cc < 4; ++cc) {
    #pragma unroll
    for (int kh = 0; kh < 3; ++kh) {
      // (1) A global->reg, issued EARLY (before barrier; regs only, safe)
      u32x4 areg[6];
      #pragma unroll
      for (int i = 0; i < 6; ++i)
        areg[i] = *(const u32x4*)(wcg + kh*49152 + srcA[i] + cc*32);
      __syncthreads();                 // readers of lds_a/lds_b done
      // (2) B direct gload_lds (per cc), A ds_write (padded, conflict-free)
      if (kh == 0) {
        #pragma unroll
        for (int i = 0; i < 7; ++i)
          GLOAD16(xtg + srcB[i] + cc*32, lds_b + (i*256 + wv*64)*8);
      }
      #pragma unroll
      for (int i = 0; i < 6; ++i)
        *(u32x4*)(lds_a + dstA[i]) = areg[i];
      __syncthreads();                 // staged data ready
      // (3) compute: 3 kwl groups, pure LDS + MFMA
      #pragma unroll
      for (int kwl = 0; kwl < 3; ++kwl) {
        bf16x8 af[4];
        #pragma unroll
        for (int mo = 0; mo < 4; ++mo)
          af[mo] = *(const bf16x8*)(lds_a + kwl*AKWS + aRead + mo*(16*ACS));
        bf16x8 bfr[7];
        #pragma unroll
        for (int f = 0; f < 7; ++f)
          bfr[f] = *(const bf16x8*)(lds_b + xoff[f] + kh*RS + kwl*CS);
        #pragma unroll
        for (int mo = 0; mo < 4; ++mo)
          #pragma unroll
          for (int f = 0; f < 7; ++f)
            acc[mo][f] = __builtin_amdgcn_mfma_f32_16x16x32_bf16(af[mo], bfr[f], acc[mo][f], 0, 0, 0);
      }
    }
  }

  float* ob = out + (size_t)b*NCO*NHW;
  #pragma unroll
  for (int mo = 0; mo < 4; ++mo) {
    #pragma unroll
    for (int rg = 0; rg < 4; ++rg) {
      const int co = wm*64 + mo*16 + kg*4 + rg;
      const float bv = bc[b*NCO + co];
      float* orow = ob + (size_t)co*NHW;
      #pragma unroll
      for (int f = 0; f < 7; ++f) {
        int pos = wn*112 + f*16 + li;
        int rB = pos / 56;
        int cB = pos - rB*56;
        orow[(r0 + rB)*56 + cB] = acc[mo][f][rg] + bv;
      }
    }
  }
}

extern "C" void kernel_launch(void* const* d_in, const int* in_sizes, int n_in,
                              void* d_out, int out_size, void* d_ws, size_t ws_size,
                              hipStream_t stream) {
  const float* x   = (const float*)d_in[0];
  const float* W   = (const float*)d_in[1];
  const float* bia = (const float*)d_in[2];
  const float* aw1 = (const float*)d_in[3];
  const float* aw2 = (const float*)d_in[4];
  float* out = (float*)d_out;
  char* ws = (char*)d_ws;
  float* attn   = (float*)(ws + WS_ATTN);
  float* bcm    = (float*)(ws + WS_BC);
  float* rowsum = (float*)(ws + WS_ROWSUM);
  __hip_bfloat16* wc = (__hip_bfloat16*)(ws + WS_WC);
  __hip_bfloat16* xt = (__hip_bfloat16*)(ws + WS_XT);

  xt_kernel<<<NB*58, 256, 0, stream>>>(x, xt, rowsum);
  attn_kernel<<<NB, 128, 0, stream>>>(rowsum, aw1, aw2, bia, attn, bcm);
  combine_kernel<<<256, 256, 0, stream>>>(W, attn, wc);
  conv_kernel<<<448, 256, 0, stream>>>((const unsigned short*)xt,
                                       (const unsigned short*)wc, bcm, out);
}